// Round 6
// baseline (467.890 us; speedup 1.0000x reference)
//
#include <hip/hip_runtime.h>

#define B_ 128
#define T_ 512
#define NIN_ 12
#define H_ 512
#define NOUT_ 4
#define DT_ 0.001f
#define CH 32               // timesteps per barrier interval
#define NC (T_ / CH)        // 16 chunks

typedef unsigned long long ull;

// Device-global weight transposes (fully rewritten every launch -> graph-safe).
__device__ __align__(16) float g_W1t[H_ * H_];   // g_W1t[h][n] = w_l1_in[n][h]
__device__ __align__(16) float g_WRt[H_ * H_];   // g_WRt[h][n] = w_l1_rec[n][h]

__device__ __forceinline__ float clamp01(float v) { return fminf(fmaxf(v, 0.0f), 1.0f); }

__global__ void transpose_pair(const float* __restrict__ a, const float* __restrict__ bsrc) {
  __shared__ float tile[32][33];
  const float* src = blockIdx.z ? bsrc : a;
  float* dst = blockIdx.z ? g_WRt : g_W1t;
  const int bx = blockIdx.x * 32, by = blockIdx.y * 32;
  const int tx = threadIdx.x, ty = threadIdx.y;  // 32x8
#pragma unroll
  for (int k = 0; k < 32; k += 8)
    tile[ty + k][tx] = src[(size_t)(by + ty + k) * H_ + bx + tx];
  __syncthreads();
#pragma unroll
  for (int k = 0; k < 32; k += 8)
    dst[(size_t)(bx + ty + k) * H_ + by + tx] = tile[tx][ty + k];
}

// One block per batch row: 5 waves (320 threads).
//  waves 0..3 (producer): encoder LIF. Lane j of wave w owns neurons 8j+w and 8j+w+4
//    (ballot slots w and w+4). Writes per-step spike masks to LDS ms[t][slot].
//  wave 4 (consumer): layer-1 LIF recurrence + LI output, lane l owns neurons 8l+s.
//    Runs 2 chunks behind the producers (lag-2 => next-step mask prefetch is always
//    barrier-separated from concurrent producer writes).
//  Per step, wave 4 extracts the NEXT step's encoder spike indices (wave-uniform) and
//  issues the W1t row loads one step early -> gather latency off the serial chain.
__global__ __launch_bounds__(320, 1) void snn_fused(
    const float* __restrict__ x, const float* __restrict__ w_in,
    const float* __restrict__ w_out,
    const float* __restrict__ tse, const float* __restrict__ tme,
    const float* __restrict__ ts1, const float* __restrict__ tm1,
    const float* __restrict__ tso, const float* __restrict__ tmo,
    float* __restrict__ out)
{
  const int b = blockIdx.x;
  const int tid = threadIdx.x;
  const int wave = tid >> 6;
  const int lane = tid & 63;

  __shared__ float4 xs[T_ * 3];                  // 24 KB: whole x[b]
  __shared__ __align__(16) ull ms[T_][8];        // 32 KB: all spike masks

  const float4* xg = (const float4*)(x + (size_t)b * T_ * NIN_);
  for (int i = tid; i < T_ * 3; i += 320) xs[i] = xg[i];

  // ---- producer state ----
  float winA[NIN_], winB[NIN_];
  float aeA = 0.f, beA = 0.f, aeB = 0.f, beB = 0.f;
  float evA = 0.f, eiA = 0.f, evB = 0.f, eiB = 0.f;
  if (wave < 4) {
    const int nA = (lane << 3) + wave;
    const int nB = nA + 4;
#pragma unroll
    for (int i = 0; i < NIN_; ++i) {
      winA[i] = w_in[nA * NIN_ + i];
      winB[i] = w_in[nB * NIN_ + i];
    }
    aeA = DT_ * clamp01(tme[nA]); beA = DT_ * clamp01(tse[nA]);
    aeB = DT_ * clamp01(tme[nB]); beB = DT_ * clamp01(tse[nB]);
  }

  // ---- consumer state ----
  float a1[8], b1[8], v1[8], i1[8];
  ull zp[8], cm[8];
  int j0 = -1, j1 = -1, j2 = -1, j3 = -1, kc = 0;
  float4 r0a = {0,0,0,0}, r0b = {0,0,0,0}, r1a = {0,0,0,0}, r1b = {0,0,0,0};
  float4 r2a = {0,0,0,0}, r2b = {0,0,0,0}, r3a = {0,0,0,0}, r3b = {0,0,0,0};
  float ao = 0.f, bo = 0.f, sov = 0.f, soi = 0.f;
#pragma unroll
  for (int s = 0; s < 8; ++s) { v1[s] = 0.f; i1[s] = 0.f; a1[s] = 0.f; b1[s] = 0.f; zp[s] = 0ULL; cm[s] = 0ULL; }
  if (wave == 4) {
    const float4* tm14 = (const float4*)tm1;
    const float4* ts14 = (const float4*)ts1;
    const float4 ta = tm14[2 * lane], tb = tm14[2 * lane + 1];
    const float4 sa = ts14[2 * lane], sb = ts14[2 * lane + 1];
    a1[0] = DT_ * clamp01(ta.x); a1[1] = DT_ * clamp01(ta.y);
    a1[2] = DT_ * clamp01(ta.z); a1[3] = DT_ * clamp01(ta.w);
    a1[4] = DT_ * clamp01(tb.x); a1[5] = DT_ * clamp01(tb.y);
    a1[6] = DT_ * clamp01(tb.z); a1[7] = DT_ * clamp01(tb.w);
    b1[0] = DT_ * clamp01(sa.x); b1[1] = DT_ * clamp01(sa.y);
    b1[2] = DT_ * clamp01(sa.z); b1[3] = DT_ * clamp01(sa.w);
    b1[4] = DT_ * clamp01(sb.x); b1[5] = DT_ * clamp01(sb.y);
    b1[6] = DT_ * clamp01(sb.z); b1[7] = DT_ * clamp01(sb.w);
    ao = DT_ * clamp01(tmo[0]); bo = DT_ * clamp01(tso[0]);
  }
  const float* wo = w_out + (lane & 3) * H_;

  // Extract next-step spike list from ms[tt] and issue W1t row loads early.
  auto extract = [&](int tt) {
    const ulonglong2* mp = (const ulonglong2*)&ms[tt][0];
    const ulonglong2 q0 = mp[0], q1 = mp[1], q2 = mp[2], q3 = mp[3];
    cm[0] = q0.x; cm[1] = q0.y; cm[2] = q1.x; cm[3] = q1.y;
    cm[4] = q2.x; cm[5] = q2.y; cm[6] = q3.x; cm[7] = q3.y;
    j0 = j1 = j2 = j3 = -1; kc = 0;
    if (cm[0] | cm[1] | cm[2] | cm[3] | cm[4] | cm[5] | cm[6] | cm[7]) {
#pragma unroll
      for (int s = 0; s < 8; ++s) {
        ull m = cm[s];
        while (m) {
          const int jj = __builtin_ctzll(m); m &= m - 1;
          const int hs = (jj << 3) + s;
          if (kc == 0) j0 = hs; else if (kc == 1) j1 = hs;
          else if (kc == 2) j2 = hs; else if (kc == 3) j3 = hs;
          ++kc;
        }
      }
    }
    const float4* W4 = (const float4*)g_W1t;
    if (j0 >= 0) { r0a = W4[(size_t)j0 * (H_/4) + 2*lane]; r0b = W4[(size_t)j0 * (H_/4) + 2*lane + 1]; }
    if (j1 >= 0) { r1a = W4[(size_t)j1 * (H_/4) + 2*lane]; r1b = W4[(size_t)j1 * (H_/4) + 2*lane + 1]; }
    if (j2 >= 0) { r2a = W4[(size_t)j2 * (H_/4) + 2*lane]; r2b = W4[(size_t)j2 * (H_/4) + 2*lane + 1]; }
    if (j3 >= 0) { r3a = W4[(size_t)j3 * (H_/4) + 2*lane]; r3b = W4[(size_t)j3 * (H_/4) + 2*lane + 1]; }
  };

  __syncthreads();  // xs staged

  for (int itv = 0; itv < NC + 2; ++itv) {
    if (wave < 4) {
      if (itv < NC) {
        const int t0 = itv * CH;
#pragma unroll 2
        for (int tc = 0; tc < CH; ++tc) {
          const int t = t0 + tc;
          const float4 xa = xs[t*3 + 0], xb = xs[t*3 + 1], xc = xs[t*3 + 2];
          float cA = 0.f, cB = 0.f;
          cA = fmaf(xa.x, winA[0], cA);  cB = fmaf(xa.x, winB[0], cB);
          cA = fmaf(xa.y, winA[1], cA);  cB = fmaf(xa.y, winB[1], cB);
          cA = fmaf(xa.z, winA[2], cA);  cB = fmaf(xa.z, winB[2], cB);
          cA = fmaf(xa.w, winA[3], cA);  cB = fmaf(xa.w, winB[3], cB);
          cA = fmaf(xb.x, winA[4], cA);  cB = fmaf(xb.x, winB[4], cB);
          cA = fmaf(xb.y, winA[5], cA);  cB = fmaf(xb.y, winB[5], cB);
          cA = fmaf(xb.z, winA[6], cA);  cB = fmaf(xb.z, winB[6], cB);
          cA = fmaf(xb.w, winA[7], cA);  cB = fmaf(xb.w, winB[7], cB);
          cA = fmaf(xc.x, winA[8], cA);  cB = fmaf(xc.x, winB[8], cB);
          cA = fmaf(xc.y, winA[9], cA);  cB = fmaf(xc.y, winB[9], cB);
          cA = fmaf(xc.z, winA[10], cA); cB = fmaf(xc.z, winB[10], cB);
          cA = fmaf(xc.w, winA[11], cA); cB = fmaf(xc.w, winB[11], cB);

          float vd = evA + aeA * (eiA - evA);
          float id = eiA - beA * eiA;
          const bool zA = (vd - 1.0f) > 0.0f;
          evA = zA ? 0.0f : vd;
          eiA = id + cA;
          const ull mA = __ballot(zA);

          vd = evB + aeB * (eiB - evB);
          id = eiB - beB * eiB;
          const bool zB = (vd - 1.0f) > 0.0f;
          evB = zB ? 0.0f : vd;
          eiB = id + cB;
          const ull mB = __ballot(zB);

          if (lane == 0) { ms[t][wave] = mA; ms[t][wave + 4] = mB; }
        }
      }
    } else {
      if (itv >= 2) {
        const int t0 = (itv - 2) * CH;
        if (t0 == 0) extract(0);
#pragma unroll 1
        for (int tc = 0; tc < CH; ++tc) {
          const int t = t0 + tc;
          // layer-1 LIF decay + spike (state from t-1)
          ull mz[8];
#pragma unroll
          for (int s = 0; s < 8; ++s) {
            const float vd = v1[s] + a1[s] * (i1[s] - v1[s]);
            const float id = i1[s] - b1[s] * i1[s];
            const bool z = (vd - 1.0f) > 0.0f;
            v1[s] = z ? 0.0f : vd;
            i1[s] = id;
            mz[s] = __ballot(z);
          }
          // encoder drive: rows preloaded one step ahead
          if (kc > 0) { i1[0]+=r0a.x; i1[1]+=r0a.y; i1[2]+=r0a.z; i1[3]+=r0a.w;
                        i1[4]+=r0b.x; i1[5]+=r0b.y; i1[6]+=r0b.z; i1[7]+=r0b.w; }
          if (kc > 1) { i1[0]+=r1a.x; i1[1]+=r1a.y; i1[2]+=r1a.z; i1[3]+=r1a.w;
                        i1[4]+=r1b.x; i1[5]+=r1b.y; i1[6]+=r1b.z; i1[7]+=r1b.w; }
          if (kc > 2) { i1[0]+=r2a.x; i1[1]+=r2a.y; i1[2]+=r2a.z; i1[3]+=r2a.w;
                        i1[4]+=r2b.x; i1[5]+=r2b.y; i1[6]+=r2b.z; i1[7]+=r2b.w; }
          if (kc > 3) { i1[0]+=r3a.x; i1[1]+=r3a.y; i1[2]+=r3a.z; i1[3]+=r3a.w;
                        i1[4]+=r3b.x; i1[5]+=r3b.y; i1[6]+=r3b.z; i1[7]+=r3b.w; }
          if (kc > 4) {  // rare overflow: synchronous gather for spikes 4..kc-1
            int skip = 4;
#pragma unroll
            for (int s = 0; s < 8; ++s) {
              ull m = cm[s];
              while (m) {
                const int jj = __builtin_ctzll(m); m &= m - 1;
                if (skip > 0) { --skip; continue; }
                const float4* r = (const float4*)(g_W1t + (size_t)((jj << 3) + s) * H_);
                const float4 ra = r[2*lane], rb = r[2*lane + 1];
                i1[0]+=ra.x; i1[1]+=ra.y; i1[2]+=ra.z; i1[3]+=ra.w;
                i1[4]+=rb.x; i1[5]+=rb.y; i1[6]+=rb.z; i1[7]+=rb.w;
              }
            }
          }
          // recurrent drive from z1 of previous step (cold path)
          if (zp[0]|zp[1]|zp[2]|zp[3]|zp[4]|zp[5]|zp[6]|zp[7]) {
#pragma unroll
            for (int s = 0; s < 8; ++s) {
              ull m = zp[s];
              while (m) {
                const int jj = __builtin_ctzll(m); m &= m - 1;
                const float4* r = (const float4*)(g_WRt + (size_t)((jj << 3) + s) * H_);
                const float4 ra = r[2*lane], rb = r[2*lane + 1];
                i1[0]+=ra.x; i1[1]+=ra.y; i1[2]+=ra.z; i1[3]+=ra.w;
                i1[4]+=rb.x; i1[5]+=rb.y; i1[6]+=rb.z; i1[7]+=rb.w;
              }
            }
          }
          // output projection from z1 of THIS step (cold path)
          float oin = 0.f;
          if (mz[0]|mz[1]|mz[2]|mz[3]|mz[4]|mz[5]|mz[6]|mz[7]) {
#pragma unroll
            for (int s = 0; s < 8; ++s) {
              ull m = mz[s];
              while (m) {
                const int jj = __builtin_ctzll(m); m &= m - 1;
                oin += wo[(jj << 3) + s];
              }
            }
          }
          // LI output: v uses OLD i, then i decays and adds out_in
          sov = sov + ao * (soi - sov);
          soi = soi - bo * soi + oin;
          if (lane < NOUT_) out[((size_t)t * B_ + b) * NOUT_ + lane] = sov;
#pragma unroll
          for (int s = 0; s < 8; ++s) zp[s] = mz[s];
          // prefetch next step (lag-2 guarantees masks are barrier-separated)
          int tn = t + 1; if (tn >= T_) tn = T_ - 1;
          extract(tn);
        }
      }
    }
    __syncthreads();
  }
}

extern "C" void kernel_launch(void* const* d_in, const int* in_sizes, int n_in,
                              void* d_out, int out_size, void* d_ws, size_t ws_size,
                              hipStream_t stream) {
  const float* x    = (const float*)d_in[0];
  const float* w_in = (const float*)d_in[1];
  const float* w1   = (const float*)d_in[2];
  const float* wrec = (const float*)d_in[3];
  const float* wout = (const float*)d_in[4];
  const float* tse  = (const float*)d_in[5];
  const float* tme  = (const float*)d_in[6];
  const float* ts1  = (const float*)d_in[7];
  const float* tm1  = (const float*)d_in[8];
  const float* tso  = (const float*)d_in[9];
  const float* tmo  = (const float*)d_in[10];
  float* out = (float*)d_out;

  transpose_pair<<<dim3(16, 16, 2), dim3(32, 8), 0, stream>>>(w1, wrec);
  snn_fused<<<dim3(B_), dim3(320), 0, stream>>>(
      x, w_in, wout, tse, tme, ts1, tm1, tso, tmo, out);
}

// Round 8
// 259.451 us; speedup vs baseline: 1.8034x; 1.8034x over previous
//
#include <hip/hip_runtime.h>

#define B_ 128
#define T_ 512
#define NIN_ 12
#define H_ 512
#define NOUT_ 4
#define DT_ 0.001f

typedef unsigned long long ull;

// Device-global scratch (fully rewritten every launch -> graph-safe).
__device__ __align__(16) float g_W1t[H_ * H_];   // g_W1t[h][n] = w_l1_in[n][h]
__device__ __align__(16) float g_WRt[H_ * H_];   // g_WRt[h][n] = w_l1_rec[n][h]
__device__ __align__(16) ull g_masks[B_ * T_ * 8];  // [b][t][slot]; bit j of slot s = neuron 8j+s
__device__ __align__(16) ull g_flags[B_ * 8 * 8];   // [b][win=t>>6][slot]: bit (t&63) = any spike in slot at t

__device__ __forceinline__ float clamp01(float v) { return fminf(fmaxf(v, 0.0f), 1.0f); }

// LDS-tiled transpose of w_l1_in / w_l1_rec into device globals.
__global__ void transpose_pair(const float* __restrict__ a, const float* __restrict__ bsrc) {
  __shared__ float tile[32][33];
  const float* src = blockIdx.z ? bsrc : a;
  float* dst = blockIdx.z ? g_WRt : g_W1t;
  const int bx = blockIdx.x * 32, by = blockIdx.y * 32;
  const int tx = threadIdx.x, ty = threadIdx.y;  // 32x8
#pragma unroll
  for (int k = 0; k < 32; k += 8)
    tile[ty + k][tx] = src[(size_t)(by + ty + k) * H_ + bx + tx];
  __syncthreads();
#pragma unroll
  for (int k = 0; k < 32; k += 8)
    dst[(size_t)(bx + ty + k) * H_ + by + tx] = tile[tx][ty + k];
}

// Phase 1: encoder LIF, parallel across (b, h). One thread = one neuron.
// grid (B, 2) x block 256: wave w of block-half g owns slot s = g*4+w, lane j -> neuron 8j+s.
// Emits per-step ballots to g_masks and a per-window flag bitstream to g_flags
// (bit t&63 set iff this slot spiked at t) -- built entirely in uniform registers.
__global__ __launch_bounds__(256, 1) void snn_phase1(
    const float* __restrict__ x, const float* __restrict__ w_in,
    const float* __restrict__ tse, const float* __restrict__ tme) {
  const int b = blockIdx.x;
  const int g = blockIdx.y;
  const int w = threadIdx.x >> 6;
  const int j = threadIdx.x & 63;
  const int s = g * 4 + w;
  const int n = (j << 3) + s;

  __shared__ float4 xs[T_ * 3];  // 24 KB: whole x[b]
  const float4* xg = (const float4*)(x + (size_t)b * T_ * NIN_);
  for (int i = threadIdx.x; i < T_ * 3; i += 256) xs[i] = xg[i];

  float win[NIN_];
#pragma unroll
  for (int i = 0; i < NIN_; ++i) win[i] = w_in[n * NIN_ + i];
  const float ae = DT_ * clamp01(tme[n]);
  const float be = DT_ * clamp01(tse[n]);
  float ev = 0.f, ei = 0.f;
  ull* mout = g_masks + (size_t)b * T_ * 8 + s;
  ull flag = 0;
  __syncthreads();

#pragma unroll 4
  for (int t = 0; t < T_; ++t) {
    const float4 xa = xs[t * 3 + 0], xb = xs[t * 3 + 1], xc = xs[t * 3 + 2];
    float c0 = 0.f, c1 = 0.f, c2 = 0.f, c3 = 0.f;
    c0 = fmaf(xa.x, win[0], c0); c1 = fmaf(xa.y, win[1], c1);
    c2 = fmaf(xa.z, win[2], c2); c3 = fmaf(xa.w, win[3], c3);
    c0 = fmaf(xb.x, win[4], c0); c1 = fmaf(xb.y, win[5], c1);
    c2 = fmaf(xb.z, win[6], c2); c3 = fmaf(xb.w, win[7], c3);
    c0 = fmaf(xc.x, win[8], c0); c1 = fmaf(xc.y, win[9], c1);
    c2 = fmaf(xc.z, win[10], c2); c3 = fmaf(xc.w, win[11], c3);
    const float c = (c0 + c1) + (c2 + c3);

    const float vdec = ev + ae * (ei - ev);
    const float idec = ei - be * ei;
    const bool ze = (vdec - 1.0f) > 0.0f;
    ev = ze ? 0.0f : vdec;
    ei = idec + c;
    const ull m = __ballot(ze);
    if (j == 0) mout[(size_t)t * 8] = m;
    if (m) flag |= 1ull << (t & 63);
    if ((t & 63) == 63) {
      if (j == 0) g_flags[((size_t)b * 8 + (t >> 6)) * 8 + s] = flag;
      flag = 0;
    }
  }
}

// Phase 2: layer-1 LIF recurrence + LI output. One wave per batch row, lane l owns
// neurons 8l+s. Fast path (no spikes this step) touches NO memory except the output
// store. Flags are loaded once per 64-step window (prefetched a window ahead);
// flagged steps load masks (prefetched 1 step early when possible) and gather
// W1t rows synchronously.
__global__ __launch_bounds__(64, 1) void snn_phase2(
    const float* __restrict__ w_out,
    const float* __restrict__ ts1, const float* __restrict__ tm1,
    const float* __restrict__ tso, const float* __restrict__ tmo,
    float* __restrict__ out) {
  const int b = blockIdx.x;
  const int l = threadIdx.x;

  float a1[8], b1[8], v1[8], i1[8];
#pragma unroll
  for (int s = 0; s < 8; ++s) {
    const int n = (l << 3) + s;
    a1[s] = DT_ * clamp01(tm1[n]);
    b1[s] = DT_ * clamp01(ts1[n]);
    v1[s] = 0.f; i1[s] = 0.f;
  }
  const float ao = DT_ * clamp01(tmo[0]);
  const float bo = DT_ * clamp01(tso[0]);
  float sov = 0.f, soi = 0.f;
  const float* wo = w_out + (l & 3) * H_;

  ull zp[8];
#pragma unroll
  for (int s = 0; s < 8; ++s) zp[s] = 0ULL;

  const ull* __restrict__ mb = g_masks + (size_t)b * T_ * 8;
  const ull* __restrict__ fb = g_flags + (size_t)b * 64;

  // window-0 flags (synchronous once)
  ull wf;
  {
    const ulonglong2* fp = (const ulonglong2*)fb;
    const ulonglong2 p0 = fp[0], p1 = fp[1], p2 = fp[2], p3 = fp[3];
    wf = p0.x | p0.y | p1.x | p1.y | p2.x | p2.y | p3.x | p3.y;
  }

  ulonglong2 pmA = {0,0}, pmB = {0,0}, pmC = {0,0}, pmD = {0,0};
  bool pmv = false;

  for (int win = 0; win < 8; ++win) {
    // issue next window's flag loads now; OR'd at window end (latency hidden by 64 steps)
    ulonglong2 f0 = {0,0}, f1 = {0,0}, f2 = {0,0}, f3 = {0,0};
    if (win < 7) {
      const ulonglong2* fp = (const ulonglong2*)(fb + (size_t)(win + 1) * 8);
      f0 = fp[0]; f1 = fp[1]; f2 = fp[2]; f3 = fp[3];
    }
    const int t0 = win * 64;
#pragma unroll 1
    for (int tc = 0; tc < 64; ++tc) {
      const int t = t0 + tc;

      // layer-1 LIF decay + spike (state from t-1)
      ull mz[8];
#pragma unroll
      for (int s = 0; s < 8; ++s) {
        const float vd = v1[s] + a1[s] * (i1[s] - v1[s]);
        const float id = i1[s] - b1[s] * i1[s];
        const bool z = (vd - 1.0f) > 0.0f;
        v1[s] = z ? 0.0f : vd;
        i1[s] = id;
        mz[s] = __ballot(z);
      }

      // encoder drive: only on flagged steps
      if ((wf >> tc) & 1) {
        ull cm8[8];
        if (pmv) {
          cm8[0] = pmA.x; cm8[1] = pmA.y; cm8[2] = pmB.x; cm8[3] = pmB.y;
          cm8[4] = pmC.x; cm8[5] = pmC.y; cm8[6] = pmD.x; cm8[7] = pmD.y;
        } else {
          const ulonglong2* mp = (const ulonglong2*)(mb + (size_t)t * 8);
          const ulonglong2 q0 = mp[0], q1 = mp[1], q2 = mp[2], q3 = mp[3];
          cm8[0] = q0.x; cm8[1] = q0.y; cm8[2] = q1.x; cm8[3] = q1.y;
          cm8[4] = q2.x; cm8[5] = q2.y; cm8[6] = q3.x; cm8[7] = q3.y;
        }
        pmv = false;
#pragma unroll
        for (int s = 0; s < 8; ++s) {
          ull m = cm8[s];
          while (m) {
            const int jj = __builtin_ctzll(m); m &= m - 1;
            const float4* r = (const float4*)(g_W1t + (size_t)((jj << 3) + s) * H_);
            const float4 ra = r[2 * l], rb = r[2 * l + 1];
            i1[0] += ra.x; i1[1] += ra.y; i1[2] += ra.z; i1[3] += ra.w;
            i1[4] += rb.x; i1[5] += rb.y; i1[6] += rb.z; i1[7] += rb.w;
          }
        }
      }

      // recurrent drive from z1 of previous step (cold path; z1 rarely/never fires)
      if (zp[0] | zp[1] | zp[2] | zp[3] | zp[4] | zp[5] | zp[6] | zp[7]) {
#pragma unroll
        for (int s = 0; s < 8; ++s) {
          ull m = zp[s];
          while (m) {
            const int jj = __builtin_ctzll(m); m &= m - 1;
            const float4* r = (const float4*)(g_WRt + (size_t)((jj << 3) + s) * H_);
            const float4 ra = r[2 * l], rb = r[2 * l + 1];
            i1[0] += ra.x; i1[1] += ra.y; i1[2] += ra.z; i1[3] += ra.w;
            i1[4] += rb.x; i1[5] += rb.y; i1[6] += rb.z; i1[7] += rb.w;
          }
        }
      }

      // output projection from z1 of THIS step (cold path)
      float oin = 0.f;
      if (mz[0] | mz[1] | mz[2] | mz[3] | mz[4] | mz[5] | mz[6] | mz[7]) {
#pragma unroll
        for (int s = 0; s < 8; ++s) {
          ull m = mz[s];
          while (m) {
            const int jj = __builtin_ctzll(m); m &= m - 1;
            oin += wo[(jj << 3) + s];
          }
        }
      }

      // LI output: v uses OLD i, then i decays and adds out_in
      sov = sov + ao * (soi - sov);
      soi = soi - bo * soi + oin;
      if (l < NOUT_) out[((size_t)t * B_ + b) * NOUT_ + l] = sov;

#pragma unroll
      for (int s = 0; s < 8; ++s) zp[s] = mz[s];

      // prefetch next step's masks if it is flagged (same window only)
      if (tc < 63 && ((wf >> (tc + 1)) & 1) && !pmv) {
        const ulonglong2* mp = (const ulonglong2*)(mb + (size_t)(t + 1) * 8);
        pmA = mp[0]; pmB = mp[1]; pmC = mp[2]; pmD = mp[3];
        pmv = true;
      }
    }
    wf = f0.x | f0.y | f1.x | f1.y | f2.x | f2.y | f3.x | f3.y;
    pmv = false;  // never carried across a window boundary
  }
}

extern "C" void kernel_launch(void* const* d_in, const int* in_sizes, int n_in,
                              void* d_out, int out_size, void* d_ws, size_t ws_size,
                              hipStream_t stream) {
  const float* x    = (const float*)d_in[0];
  const float* w_in = (const float*)d_in[1];
  const float* w1   = (const float*)d_in[2];
  const float* wrec = (const float*)d_in[3];
  const float* wout = (const float*)d_in[4];
  const float* tse  = (const float*)d_in[5];
  const float* tme  = (const float*)d_in[6];
  const float* ts1  = (const float*)d_in[7];
  const float* tm1  = (const float*)d_in[8];
  const float* tso  = (const float*)d_in[9];
  const float* tmo  = (const float*)d_in[10];
  float* out = (float*)d_out;

  transpose_pair<<<dim3(16, 16, 2), dim3(32, 8), 0, stream>>>(w1, wrec);
  snn_phase1<<<dim3(B_, 2), dim3(256), 0, stream>>>(x, w_in, tse, tme);
  snn_phase2<<<dim3(B_), dim3(64), 0, stream>>>(wout, ts1, tm1, tso, tmo, out);
}

// Round 11
// 166.982 us; speedup vs baseline: 2.8020x; 1.5538x over previous
//
#include <hip/hip_runtime.h>

#define B_ 128
#define T_ 512
#define NIN_ 12
#define H_ 512
#define NOUT_ 4
#define DT_ 0.001f

typedef unsigned long long ull;

// Device-global scratch (fully rewritten every launch -> graph-safe).
__device__ __align__(16) float g_W1t[H_ * H_];      // g_W1t[h][n] = w_l1_in[n][h]
__device__ __align__(16) float g_WRt[H_ * H_];      // g_WRt[h][n] = w_l1_rec[n][h]
__device__ __align__(16) ull g_masks[B_ * T_ * 8];  // [b][t][slot]; bit j of slot s = neuron 8j+s
__device__ __align__(16) ull g_flags[B_ * 8 * 8];   // [b][win][slot]: bit (t&63) = spike in slot at t
__device__ unsigned g_tstar[B_];                    // first layer-1 threshold crossing per batch

__device__ __forceinline__ float clamp01(float v) { return fminf(fmaxf(v, 0.0f), 1.0f); }

// Transpose w_l1_in / w_l1_rec into device globals; also zero d_out and init g_tstar.
__global__ void transpose_pair(const float* __restrict__ a, const float* __restrict__ bsrc,
                               float* __restrict__ out) {
  // side duty: zero the 1 MB output + init tstar (grid covers 131072 threads)
  const int gtid = (((blockIdx.z * gridDim.y + blockIdx.y) * gridDim.x + blockIdx.x) * 256)
                   + threadIdx.y * 32 + threadIdx.x;
  if (gtid < (T_ * B_ * NOUT_) / 4) {
    float4 z; z.x = 0.f; z.y = 0.f; z.z = 0.f; z.w = 0.f;
    ((float4*)out)[gtid] = z;
  }
  if (gtid < B_) g_tstar[gtid] = T_;

  __shared__ float tile[32][33];
  const float* src = blockIdx.z ? bsrc : a;
  float* dst = blockIdx.z ? g_WRt : g_W1t;
  const int bx = blockIdx.x * 32, by = blockIdx.y * 32;
  const int tx = threadIdx.x, ty = threadIdx.y;  // 32x8
#pragma unroll
  for (int k = 0; k < 32; k += 8)
    tile[ty + k][tx] = src[(size_t)(by + ty + k) * H_ + bx + tx];
  __syncthreads();
#pragma unroll
  for (int k = 0; k < 32; k += 8)
    dst[(size_t)(bx + ty + k) * H_ + by + tx] = tile[tx][ty + k];
}

// Phase 1: encoder LIF, one thread per (b, neuron). grid (B,2) x 256.
// 4-deep software pipeline: x for step t+4 is prefetched into a register ring while
// step t computes -> LDS latency hidden; serial chain is only the 3-op ev update.
__global__ __launch_bounds__(256, 1) void snn_phase1(
    const float* __restrict__ x, const float* __restrict__ w_in,
    const float* __restrict__ tse, const float* __restrict__ tme) {
  const int b = blockIdx.x;
  const int g = blockIdx.y;
  const int w = threadIdx.x >> 6;
  const int j = threadIdx.x & 63;
  const int s = g * 4 + w;
  const int n = (j << 3) + s;

  __shared__ float4 xs[(T_ + 4) * 3];  // pad: prefetch reads past T_ harmlessly
  const float4* xg = (const float4*)(x + (size_t)b * T_ * NIN_);
  for (int i = threadIdx.x; i < T_ * 3; i += 256) xs[i] = xg[i];

  float win[NIN_];
#pragma unroll
  for (int i = 0; i < NIN_; ++i) win[i] = w_in[n * NIN_ + i];
  const float ae = DT_ * clamp01(tme[n]);
  const float be = DT_ * clamp01(tse[n]);
  float ev = 0.f, ei = 0.f;
  ull* mout = g_masks + (size_t)b * T_ * 8 + s;
  ull* gfo = g_flags + (size_t)b * 64 + s;
  ull flag = 0;
  __syncthreads();

  float4 A0 = xs[0], A1 = xs[1],  A2 = xs[2];
  float4 B0 = xs[3], B1 = xs[4],  B2 = xs[5];
  float4 C0 = xs[6], C1 = xs[7],  C2 = xs[8];
  float4 D0 = xs[9], D1 = xs[10], D2 = xs[11];

  auto STEP = [&](float4& xa, float4& xb, float4& xc, int t) {
    float c0 = 0.f, c1 = 0.f, c2 = 0.f, c3 = 0.f;
    c0 = fmaf(xa.x, win[0], c0); c1 = fmaf(xa.y, win[1], c1);
    c2 = fmaf(xa.z, win[2], c2); c3 = fmaf(xa.w, win[3], c3);
    c0 = fmaf(xb.x, win[4], c0); c1 = fmaf(xb.y, win[5], c1);
    c2 = fmaf(xb.z, win[6], c2); c3 = fmaf(xb.w, win[7], c3);
    c0 = fmaf(xc.x, win[8], c0); c1 = fmaf(xc.y, win[9], c1);
    c2 = fmaf(xc.z, win[10], c2); c3 = fmaf(xc.w, win[11], c3);
    const float c = (c0 + c1) + (c2 + c3);
    const int pf = (t + 4) * 3;          // refill ring slot for step t+4
    xa = xs[pf]; xb = xs[pf + 1]; xc = xs[pf + 2];
    const float vdec = fmaf(ae, ei - ev, ev);
    const bool ze = vdec > 1.0f;
    const ull m = __ballot(ze);
    ev = ze ? 0.0f : vdec;
    ei = fmaf(-be, ei, ei) + c;
    if (j == 0) mout[(size_t)t * 8] = m;
    flag |= (m ? 1ull : 0ull) << (t & 63);
    if ((t & 63) == 63) { if (j == 0) gfo[(size_t)(t >> 6) * 8] = flag; flag = 0; }
  };

  for (int t = 0; t < T_; t += 4) {
    STEP(A0, A1, A2, t);
    STEP(B0, B1, B2, t + 1);
    STEP(C0, C1, C2, t + 2);
    STEP(D0, D1, D2, t + 3);
  }
}

// Phase 2 SPECULATE: one thread per (b, neuron); assumes NO layer-1 spikes, runs the
// then-linear (v1, i1) trajectory, records the first step where v1_dec > 1 (exact up
// to first crossing). 65536-way parallel -> no serial wave chain. grid (B,2) x 256.
__global__ __launch_bounds__(256, 1) void snn_spec(
    const float* __restrict__ ts1, const float* __restrict__ tm1) {
  const int b = blockIdx.x;
  const int n = blockIdx.y * 256 + threadIdx.x;
  const float a1 = DT_ * clamp01(tm1[n]);
  const float b1 = DT_ * clamp01(ts1[n]);
  float v1 = 0.f, i1 = 0.f;
  unsigned tstar = 0xFFFFFFFFu;

  const ull* __restrict__ mb = g_masks + (size_t)b * T_ * 8;
  const ull* __restrict__ fb = g_flags + (size_t)b * 64;

  for (int win = 0; win < 8; ++win) {
    const ulonglong2* fp = (const ulonglong2*)(fb + (size_t)win * 8);
    const ulonglong2 p0 = fp[0], p1 = fp[1], p2 = fp[2], p3 = fp[3];
    const ull wf = p0.x | p0.y | p1.x | p1.y | p2.x | p2.y | p3.x | p3.y;
    const int t0 = win * 64;
#pragma unroll 4
    for (int tc = 0; tc < 64; ++tc) {
      const int t = t0 + tc;
      const float vd = fmaf(a1, i1 - v1, v1);
      tstar = (vd > 1.0f) ? min(tstar, (unsigned)t) : tstar;
      v1 = vd;
      float acc = 0.f;
      if ((wf >> tc) & 1) {  // encoder spikes this step: coalesced row gathers
        const ulonglong2* mp = (const ulonglong2*)(mb + (size_t)t * 8);
        const ulonglong2 q0 = mp[0], q1 = mp[1], q2 = mp[2], q3 = mp[3];
        const ull cm8[8] = {q0.x, q0.y, q1.x, q1.y, q2.x, q2.y, q3.x, q3.y};
#pragma unroll
        for (int s = 0; s < 8; ++s) {
          ull m = cm8[s];
          while (m) {
            const int jj = __builtin_ctzll(m); m &= m - 1;
            acc += g_W1t[(size_t)((jj << 3) + s) * H_ + n];
          }
        }
      }
      i1 = fmaf(-b1, i1, i1) + acc;
    }
  }
  if (tstar != 0xFFFFFFFFu) atomicMin(&g_tstar[b], tstar);
}

// FIXUP: exact serial recurrence (round-8 phase2, proven) — runs ONLY for batches
// where speculation found a layer-1 crossing. Otherwise out stays all-zero (exact:
// z1 == 0 for all t  =>  so_i == so_v == 0).
__global__ __launch_bounds__(64, 1) void snn_fixup(
    const float* __restrict__ w_out,
    const float* __restrict__ ts1, const float* __restrict__ tm1,
    const float* __restrict__ tso, const float* __restrict__ tmo,
    float* __restrict__ out) {
  const int b = blockIdx.x;
  if (g_tstar[b] >= T_) return;  // speculation verified: nothing to fix
  const int l = threadIdx.x;

  float a1[8], b1[8], v1[8], i1[8];
#pragma unroll
  for (int s = 0; s < 8; ++s) {
    const int n = (l << 3) + s;
    a1[s] = DT_ * clamp01(tm1[n]);
    b1[s] = DT_ * clamp01(ts1[n]);
    v1[s] = 0.f; i1[s] = 0.f;
  }
  const float ao = DT_ * clamp01(tmo[0]);
  const float bo = DT_ * clamp01(tso[0]);
  float sov = 0.f, soi = 0.f;
  const float* wo = w_out + (l & 3) * H_;

  ull zp[8];
#pragma unroll
  for (int s = 0; s < 8; ++s) zp[s] = 0ULL;

  const ull* __restrict__ mb = g_masks + (size_t)b * T_ * 8;
  const ull* __restrict__ fb = g_flags + (size_t)b * 64;

  ull wf;
  {
    const ulonglong2* fp = (const ulonglong2*)fb;
    const ulonglong2 p0 = fp[0], p1 = fp[1], p2 = fp[2], p3 = fp[3];
    wf = p0.x | p0.y | p1.x | p1.y | p2.x | p2.y | p3.x | p3.y;
  }

  for (int win = 0; win < 8; ++win) {
    ulonglong2 f0 = {0,0}, f1 = {0,0}, f2 = {0,0}, f3 = {0,0};
    if (win < 7) {
      const ulonglong2* fp = (const ulonglong2*)(fb + (size_t)(win + 1) * 8);
      f0 = fp[0]; f1 = fp[1]; f2 = fp[2]; f3 = fp[3];
    }
    const int t0 = win * 64;
#pragma unroll 1
    for (int tc = 0; tc < 64; ++tc) {
      const int t = t0 + tc;
      ull mz[8];
#pragma unroll
      for (int s = 0; s < 8; ++s) {
        const float vd = v1[s] + a1[s] * (i1[s] - v1[s]);
        const float id = i1[s] - b1[s] * i1[s];
        const bool z = (vd - 1.0f) > 0.0f;
        v1[s] = z ? 0.0f : vd;
        i1[s] = id;
        mz[s] = __ballot(z);
      }
      if ((wf >> tc) & 1) {
        const ulonglong2* mp = (const ulonglong2*)(mb + (size_t)t * 8);
        const ulonglong2 q0 = mp[0], q1 = mp[1], q2 = mp[2], q3 = mp[3];
        const ull cm8[8] = {q0.x, q0.y, q1.x, q1.y, q2.x, q2.y, q3.x, q3.y};
#pragma unroll
        for (int s = 0; s < 8; ++s) {
          ull m = cm8[s];
          while (m) {
            const int jj = __builtin_ctzll(m); m &= m - 1;
            const float4* r = (const float4*)(g_W1t + (size_t)((jj << 3) + s) * H_);
            const float4 ra = r[2 * l], rb = r[2 * l + 1];
            i1[0] += ra.x; i1[1] += ra.y; i1[2] += ra.z; i1[3] += ra.w;
            i1[4] += rb.x; i1[5] += rb.y; i1[6] += rb.z; i1[7] += rb.w;
          }
        }
      }
      if (zp[0] | zp[1] | zp[2] | zp[3] | zp[4] | zp[5] | zp[6] | zp[7]) {
#pragma unroll
        for (int s = 0; s < 8; ++s) {
          ull m = zp[s];
          while (m) {
            const int jj = __builtin_ctzll(m); m &= m - 1;
            const float4* r = (const float4*)(g_WRt + (size_t)((jj << 3) + s) * H_);
            const float4 ra = r[2 * l], rb = r[2 * l + 1];
            i1[0] += ra.x; i1[1] += ra.y; i1[2] += ra.z; i1[3] += ra.w;
            i1[4] += rb.x; i1[5] += rb.y; i1[6] += rb.z; i1[7] += rb.w;
          }
        }
      }
      float oin = 0.f;
      if (mz[0] | mz[1] | mz[2] | mz[3] | mz[4] | mz[5] | mz[6] | mz[7]) {
#pragma unroll
        for (int s = 0; s < 8; ++s) {
          ull m = mz[s];
          while (m) {
            const int jj = __builtin_ctzll(m); m &= m - 1;
            oin += wo[(jj << 3) + s];
          }
        }
      }
      sov = sov + ao * (soi - sov);
      soi = soi - bo * soi + oin;
      if (l < NOUT_) out[((size_t)t * B_ + b) * NOUT_ + l] = sov;
#pragma unroll
      for (int s = 0; s < 8; ++s) zp[s] = mz[s];
    }
    wf = f0.x | f0.y | f1.x | f1.y | f2.x | f2.y | f3.x | f3.y;
  }
}

extern "C" void kernel_launch(void* const* d_in, const int* in_sizes, int n_in,
                              void* d_out, int out_size, void* d_ws, size_t ws_size,
                              hipStream_t stream) {
  const float* x    = (const float*)d_in[0];
  const float* w_in = (const float*)d_in[1];
  const float* w1   = (const float*)d_in[2];
  const float* wrec = (const float*)d_in[3];
  const float* wout = (const float*)d_in[4];
  const float* tse  = (const float*)d_in[5];
  const float* tme  = (const float*)d_in[6];
  const float* ts1  = (const float*)d_in[7];
  const float* tm1  = (const float*)d_in[8];
  const float* tso  = (const float*)d_in[9];
  const float* tmo  = (const float*)d_in[10];
  float* out = (float*)d_out;

  transpose_pair<<<dim3(16, 16, 2), dim3(32, 8), 0, stream>>>(w1, wrec, out);
  snn_phase1<<<dim3(B_, 2), dim3(256), 0, stream>>>(x, w_in, tse, tme);
  snn_spec<<<dim3(B_, 2), dim3(256), 0, stream>>>(ts1, tm1);
  snn_fixup<<<dim3(B_), dim3(64), 0, stream>>>(wout, ts1, tm1, tso, tmo, out);
}

// Round 12
// 152.295 us; speedup vs baseline: 3.0723x; 1.0964x over previous
//
#include <hip/hip_runtime.h>

#define B_ 128
#define T_ 512
#define NIN_ 12
#define H_ 512
#define NOUT_ 4
#define DT_ 0.001f

typedef unsigned long long ull;

// Device-global scratch (fully rewritten every launch -> graph-safe).
__device__ __align__(16) float g_W1t[H_ * H_];      // g_W1t[h][n] = w_l1_in[n][h]
__device__ __align__(16) float g_WRt[H_ * H_];      // g_WRt[h][n] = w_l1_rec[n][h]
__device__ __align__(16) ull g_masks[B_ * T_ * 8];  // [b][t][slot]; bit j of slot s = neuron 8j+s
__device__ __align__(16) ull g_flags[B_ * 8 * 8];   // [b][win][slot]: bit (t&63) = spike in slot at t
__device__ unsigned g_tstar[B_];                    // first layer-1 threshold crossing per batch

__device__ __forceinline__ float clamp01(float v) { return fminf(fmaxf(v, 0.0f), 1.0f); }

// Transpose w_l1_in / w_l1_rec into device globals; also zero d_out and init g_tstar.
__global__ void transpose_pair(const float* __restrict__ a, const float* __restrict__ bsrc,
                               float* __restrict__ out) {
  const int gtid = (((blockIdx.z * gridDim.y + blockIdx.y) * gridDim.x + blockIdx.x) * 256)
                   + threadIdx.y * 32 + threadIdx.x;
  if (gtid < (T_ * B_ * NOUT_) / 4) {
    float4 z; z.x = 0.f; z.y = 0.f; z.z = 0.f; z.w = 0.f;
    ((float4*)out)[gtid] = z;
  }
  if (gtid < B_) g_tstar[gtid] = T_;

  __shared__ float tile[32][33];
  const float* src = blockIdx.z ? bsrc : a;
  float* dst = blockIdx.z ? g_WRt : g_W1t;
  const int bx = blockIdx.x * 32, by = blockIdx.y * 32;
  const int tx = threadIdx.x, ty = threadIdx.y;  // 32x8
#pragma unroll
  for (int k = 0; k < 32; k += 8)
    tile[ty + k][tx] = src[(size_t)(by + ty + k) * H_ + bx + tx];
  __syncthreads();
#pragma unroll
  for (int k = 0; k < 32; k += 8)
    dst[(size_t)(bx + ty + k) * H_ + by + tx] = tile[tx][ty + k];
}

// Phase 1: encoder LIF, one thread per (b, neuron). grid (B,2) x 256.
// Ping-pong double buffer (2 x 12 float4 named registers) + sched_barrier(0) pins
// each 12-load LDS group a full 4-step group (~250cy) ahead of consumption.
__global__ __launch_bounds__(256, 1) void snn_phase1(
    const float* __restrict__ x, const float* __restrict__ w_in,
    const float* __restrict__ tse, const float* __restrict__ tme) {
  const int b = blockIdx.x;
  const int g = blockIdx.y;
  const int w = threadIdx.x >> 6;
  const int j = threadIdx.x & 63;
  const int s = g * 4 + w;
  const int n = (j << 3) + s;

  __shared__ float4 xs[(T_ + 8) * 3];  // pad: tail prefetch reads are value-dead
  const float4* xg = (const float4*)(x + (size_t)b * T_ * NIN_);
  for (int i = threadIdx.x; i < T_ * 3; i += 256) xs[i] = xg[i];

  float win[NIN_];
#pragma unroll
  for (int i = 0; i < NIN_; ++i) win[i] = w_in[n * NIN_ + i];
  const float ae = DT_ * clamp01(tme[n]);
  const float be = DT_ * clamp01(tse[n]);
  float ev = 0.f, ei = 0.f;
  ull* mout = g_masks + (size_t)b * T_ * 8 + s;
  ull* gfo = g_flags + (size_t)b * 64 + s;
  ull flag = 0;
  __syncthreads();

  float4 bufA[12], bufB[12];
#pragma unroll
  for (int q = 0; q < 12; ++q) bufA[q] = xs[q];

#define PSTEP(BUF, SLOT, TT)                                                  \
  {                                                                           \
    const float4 xa = BUF[(SLOT)*3], xb = BUF[(SLOT)*3 + 1], xc = BUF[(SLOT)*3 + 2]; \
    float c0 = 0.f, c1 = 0.f, c2 = 0.f, c3 = 0.f;                             \
    c0 = fmaf(xa.x, win[0], c0);  c1 = fmaf(xa.y, win[1], c1);                \
    c2 = fmaf(xa.z, win[2], c2);  c3 = fmaf(xa.w, win[3], c3);                \
    c0 = fmaf(xb.x, win[4], c0);  c1 = fmaf(xb.y, win[5], c1);                \
    c2 = fmaf(xb.z, win[6], c2);  c3 = fmaf(xb.w, win[7], c3);                \
    c0 = fmaf(xc.x, win[8], c0);  c1 = fmaf(xc.y, win[9], c1);                \
    c2 = fmaf(xc.z, win[10], c2); c3 = fmaf(xc.w, win[11], c3);               \
    const float c = (c0 + c1) + (c2 + c3);                                    \
    const float vdec = fmaf(ae, ei - ev, ev);                                 \
    const bool ze = vdec > 1.0f;                                              \
    const ull m = __ballot(ze);                                               \
    ev = ze ? 0.0f : vdec;                                                    \
    ei = fmaf(-be, ei, ei) + c;                                               \
    if (j == 0) mout[(size_t)(TT) * 8] = m;                                   \
    flag |= (m ? 1ull : 0ull) << ((TT) & 63);                                 \
    if (((TT) & 63) == 63) {                                                  \
      if (j == 0) gfo[(size_t)((TT) >> 6) * 8] = flag;                        \
      flag = 0;                                                               \
    }                                                                         \
  }

#pragma unroll 1
  for (int tg = 0; tg < T_; tg += 8) {
#pragma unroll
    for (int q = 0; q < 12; ++q) bufB[q] = xs[(tg + 4) * 3 + q];
    __builtin_amdgcn_sched_barrier(0);
    PSTEP(bufA, 0, tg);
    PSTEP(bufA, 1, tg + 1);
    PSTEP(bufA, 2, tg + 2);
    PSTEP(bufA, 3, tg + 3);
#pragma unroll
    for (int q = 0; q < 12; ++q) bufA[q] = xs[(tg + 8) * 3 + q];
    __builtin_amdgcn_sched_barrier(0);
    PSTEP(bufB, 0, tg + 4);
    PSTEP(bufB, 1, tg + 5);
    PSTEP(bufB, 2, tg + 6);
    PSTEP(bufB, 3, tg + 7);
  }
#undef PSTEP
}

// Phase 2 SPECULATE (event-driven): one thread per (b, neuron); assumes NO layer-1
// spikes, runs the then-linear (v1, i1) trajectory, records the first step where
// v1_dec > 1 (exact up to first crossing). Between events: pure-VALU decay loop.
// Next event's mask loads are issued one event ahead (decay run covers latency).
__global__ __launch_bounds__(256, 1) void snn_spec(
    const float* __restrict__ ts1, const float* __restrict__ tm1) {
  const int b = blockIdx.x;
  const int n = blockIdx.y * 256 + threadIdx.x;
  const float a1 = DT_ * clamp01(tm1[n]);
  const float b1 = DT_ * clamp01(ts1[n]);
  float v1 = 0.f, i1 = 0.f;
  unsigned tstar = 0xFFFFFFFFu;

  const ull* __restrict__ mb = g_masks + (size_t)b * T_ * 8;
  const ull* __restrict__ fb = g_flags + (size_t)b * 64;

  // all 8 windows' slot-OR'd flag words (uniform loads, one-time)
  ull wfs[8];
#pragma unroll
  for (int w2 = 0; w2 < 8; ++w2) {
    const ulonglong2* fp = (const ulonglong2*)(fb + (size_t)w2 * 8);
    const ulonglong2 p0 = fp[0], p1 = fp[1], p2 = fp[2], p3 = fp[3];
    wfs[w2] = p0.x | p0.y | p1.x | p1.y | p2.x | p2.y | p3.x | p3.y;
  }

#define DECAY_TO(TE)                                                \
  for (; t < (TE); ++t) {                                           \
    const float vd = fmaf(a1, i1 - v1, v1);                         \
    if (vd > 1.0f) tstar = min(tstar, (unsigned)t);                 \
    v1 = vd;                                                        \
    i1 = fmaf(-b1, i1, i1);                                         \
  }

  int t = 0;
#pragma unroll
  for (int w2 = 0; w2 < 8; ++w2) {  // full unroll -> wfs[w2] statically indexed
    ull rem = wfs[w2];
    const int wend = w2 * 64 + 64;
    int te = -1;
    ull cm[8];
    if (rem) {
      te = w2 * 64 + __builtin_ctzll(rem);
      rem &= rem - 1;
      const ulonglong2* mp = (const ulonglong2*)(mb + (size_t)te * 8);
      const ulonglong2 q0 = mp[0], q1 = mp[1], q2 = mp[2], q3 = mp[3];
      cm[0] = q0.x; cm[1] = q0.y; cm[2] = q1.x; cm[3] = q1.y;
      cm[4] = q2.x; cm[5] = q2.y; cm[6] = q3.x; cm[7] = q3.y;
    }
#pragma unroll 1
    while (te >= 0) {
      // issue NEXT event's mask loads (consumed next iteration; decay covers latency)
      int te2 = -1;
      ull nm[8] = {0, 0, 0, 0, 0, 0, 0, 0};
      if (rem) {
        te2 = w2 * 64 + __builtin_ctzll(rem);
        rem &= rem - 1;
        const ulonglong2* mp = (const ulonglong2*)(mb + (size_t)te2 * 8);
        const ulonglong2 q0 = mp[0], q1 = mp[1], q2 = mp[2], q3 = mp[3];
        nm[0] = q0.x; nm[1] = q0.y; nm[2] = q1.x; nm[3] = q1.y;
        nm[4] = q2.x; nm[5] = q2.y; nm[6] = q3.x; nm[7] = q3.y;
      }
      // spike list for THIS event (<=4 fast, overflow sync later); issue value loads
      int h0 = -1, h1 = -1, h2 = -1, h3 = -1, kc = 0;
#pragma unroll
      for (int s = 0; s < 8; ++s) {
        ull m = cm[s];
        while (m) {
          const int jj = __builtin_ctzll(m); m &= m - 1;
          const int hs = (jj << 3) + s;
          if (kc == 0) h0 = hs; else if (kc == 1) h1 = hs;
          else if (kc == 2) h2 = hs; else if (kc == 3) h3 = hs;
          ++kc;
        }
      }
      float q0v = 0.f, q1v = 0.f, q2v = 0.f, q3v = 0.f;
      if (h0 >= 0) q0v = g_W1t[(size_t)h0 * H_ + n];
      if (h1 >= 0) q1v = g_W1t[(size_t)h1 * H_ + n];
      if (h2 >= 0) q2v = g_W1t[(size_t)h2 * H_ + n];
      if (h3 >= 0) q3v = g_W1t[(size_t)h3 * H_ + n];
      float ovf = 0.f;
      if (kc > 4) {  // rare: synchronous gather for spikes 4..kc-1
        int skip = 4;
#pragma unroll
        for (int s = 0; s < 8; ++s) {
          ull m = cm[s];
          while (m) {
            const int jj = __builtin_ctzll(m); m &= m - 1;
            if (skip > 0) { --skip; continue; }
            ovf += g_W1t[(size_t)((jj << 3) + s) * H_ + n];
          }
        }
      }
      // decay up to the event (covers the loads above)
      DECAY_TO(te);
      // event step te: v uses old i; i decays then receives the drive
      const float vd = fmaf(a1, i1 - v1, v1);
      if (vd > 1.0f) tstar = min(tstar, (unsigned)te);
      v1 = vd;
      i1 = fmaf(-b1, i1, i1) + (((q0v + q1v) + (q2v + q3v)) + ovf);
      t = te + 1;
      // rotate pipeline
      te = te2;
#pragma unroll
      for (int q = 0; q < 8; ++q) cm[q] = nm[q];
    }
    DECAY_TO(wend);
  }
#undef DECAY_TO

  if (tstar != 0xFFFFFFFFu) atomicMin(&g_tstar[b], tstar);
}

// FIXUP: exact serial recurrence (round-8 phase2, HW-proven) — runs ONLY for batches
// where speculation found a layer-1 crossing. Otherwise out stays all-zero (exact:
// z1 == 0 for all t  =>  so_i == so_v == 0).
__global__ __launch_bounds__(64, 1) void snn_fixup(
    const float* __restrict__ w_out,
    const float* __restrict__ ts1, const float* __restrict__ tm1,
    const float* __restrict__ tso, const float* __restrict__ tmo,
    float* __restrict__ out) {
  const int b = blockIdx.x;
  if (g_tstar[b] >= T_) return;  // speculation verified: nothing to fix
  const int l = threadIdx.x;

  float a1[8], b1[8], v1[8], i1[8];
#pragma unroll
  for (int s = 0; s < 8; ++s) {
    const int n = (l << 3) + s;
    a1[s] = DT_ * clamp01(tm1[n]);
    b1[s] = DT_ * clamp01(ts1[n]);
    v1[s] = 0.f; i1[s] = 0.f;
  }
  const float ao = DT_ * clamp01(tmo[0]);
  const float bo = DT_ * clamp01(tso[0]);
  float sov = 0.f, soi = 0.f;
  const float* wo = w_out + (l & 3) * H_;

  ull zp[8];
#pragma unroll
  for (int s = 0; s < 8; ++s) zp[s] = 0ULL;

  const ull* __restrict__ mb = g_masks + (size_t)b * T_ * 8;
  const ull* __restrict__ fb = g_flags + (size_t)b * 64;

  ull wf;
  {
    const ulonglong2* fp = (const ulonglong2*)fb;
    const ulonglong2 p0 = fp[0], p1 = fp[1], p2 = fp[2], p3 = fp[3];
    wf = p0.x | p0.y | p1.x | p1.y | p2.x | p2.y | p3.x | p3.y;
  }

  for (int win = 0; win < 8; ++win) {
    ulonglong2 f0 = {0,0}, f1 = {0,0}, f2 = {0,0}, f3 = {0,0};
    if (win < 7) {
      const ulonglong2* fp = (const ulonglong2*)(fb + (size_t)(win + 1) * 8);
      f0 = fp[0]; f1 = fp[1]; f2 = fp[2]; f3 = fp[3];
    }
    const int t0 = win * 64;
#pragma unroll 1
    for (int tc = 0; tc < 64; ++tc) {
      const int t = t0 + tc;
      ull mz[8];
#pragma unroll
      for (int s = 0; s < 8; ++s) {
        const float vd = v1[s] + a1[s] * (i1[s] - v1[s]);
        const float id = i1[s] - b1[s] * i1[s];
        const bool z = (vd - 1.0f) > 0.0f;
        v1[s] = z ? 0.0f : vd;
        i1[s] = id;
        mz[s] = __ballot(z);
      }
      if ((wf >> tc) & 1) {
        const ulonglong2* mp = (const ulonglong2*)(mb + (size_t)t * 8);
        const ulonglong2 q0 = mp[0], q1 = mp[1], q2 = mp[2], q3 = mp[3];
        const ull cm8[8] = {q0.x, q0.y, q1.x, q1.y, q2.x, q2.y, q3.x, q3.y};
#pragma unroll
        for (int s = 0; s < 8; ++s) {
          ull m = cm8[s];
          while (m) {
            const int jj = __builtin_ctzll(m); m &= m - 1;
            const float4* r = (const float4*)(g_W1t + (size_t)((jj << 3) + s) * H_);
            const float4 ra = r[2 * l], rb = r[2 * l + 1];
            i1[0] += ra.x; i1[1] += ra.y; i1[2] += ra.z; i1[3] += ra.w;
            i1[4] += rb.x; i1[5] += rb.y; i1[6] += rb.z; i1[7] += rb.w;
          }
        }
      }
      if (zp[0] | zp[1] | zp[2] | zp[3] | zp[4] | zp[5] | zp[6] | zp[7]) {
#pragma unroll
        for (int s = 0; s < 8; ++s) {
          ull m = zp[s];
          while (m) {
            const int jj = __builtin_ctzll(m); m &= m - 1;
            const float4* r = (const float4*)(g_WRt + (size_t)((jj << 3) + s) * H_);
            const float4 ra = r[2 * l], rb = r[2 * l + 1];
            i1[0] += ra.x; i1[1] += ra.y; i1[2] += ra.z; i1[3] += ra.w;
            i1[4] += rb.x; i1[5] += rb.y; i1[6] += rb.z; i1[7] += rb.w;
          }
        }
      }
      float oin = 0.f;
      if (mz[0] | mz[1] | mz[2] | mz[3] | mz[4] | mz[5] | mz[6] | mz[7]) {
#pragma unroll
        for (int s = 0; s < 8; ++s) {
          ull m = mz[s];
          while (m) {
            const int jj = __builtin_ctzll(m); m &= m - 1;
            oin += wo[(jj << 3) + s];
          }
        }
      }
      sov = sov + ao * (soi - sov);
      soi = soi - bo * soi + oin;
      if (l < NOUT_) out[((size_t)t * B_ + b) * NOUT_ + l] = sov;
#pragma unroll
      for (int s = 0; s < 8; ++s) zp[s] = mz[s];
    }
    wf = f0.x | f0.y | f1.x | f1.y | f2.x | f2.y | f3.x | f3.y;
  }
}

extern "C" void kernel_launch(void* const* d_in, const int* in_sizes, int n_in,
                              void* d_out, int out_size, void* d_ws, size_t ws_size,
                              hipStream_t stream) {
  const float* x    = (const float*)d_in[0];
  const float* w_in = (const float*)d_in[1];
  const float* w1   = (const float*)d_in[2];
  const float* wrec = (const float*)d_in[3];
  const float* wout = (const float*)d_in[4];
  const float* tse  = (const float*)d_in[5];
  const float* tme  = (const float*)d_in[6];
  const float* ts1  = (const float*)d_in[7];
  const float* tm1  = (const float*)d_in[8];
  const float* tso  = (const float*)d_in[9];
  const float* tmo  = (const float*)d_in[10];
  float* out = (float*)d_out;

  transpose_pair<<<dim3(16, 16, 2), dim3(32, 8), 0, stream>>>(w1, wrec, out);
  snn_phase1<<<dim3(B_, 2), dim3(256), 0, stream>>>(x, w_in, tse, tme);
  snn_spec<<<dim3(B_, 2), dim3(256), 0, stream>>>(ts1, tm1);
  snn_fixup<<<dim3(B_), dim3(64), 0, stream>>>(wout, ts1, tm1, tso, tmo, out);
}